// Round 6
// baseline (525.258 us; speedup 1.0000x reference)
//
#include <hip/hip_runtime.h>
#include <stdint.h>

// ---------------------------------------------------------------------------
// NodeDropout: drop-set = jax.random.permutation(key(42), 200000)[:20000]
// (partitionable threefry), keep edge unless BOTH endpoints dropped,
// stable-compact kept edges, -1 tail.
// 3-pass edge compaction: count -> scan -> LDS-staged scatter (dense stores,
// reverse-indexed -1 tail). Contiguous-16-edges-per-thread layout, minimal
// barriers, nontemporal output stores. rank1+threshold+dropbits fused.
// ---------------------------------------------------------------------------

#define N_NODES   200000
#define N_DROP    20000
#define NEDGE     20000000
#define NBIN      65536
#define NWORDS_ND 6250          // 200000/32

// edge-pass geometry (count & scatter share it): 256 thr x 16 edges = 4096
#define FB_T      256
#define FB_PER    16
#define FB_EDGES  (FB_T*FB_PER)                     // 4096
#define FB_NB     ((NEDGE + FB_EDGES - 1)/FB_EDGES) // 4883

// native vector type for nontemporal 16B stores (HIP int4 is struct-wrapped)
typedef int v4i __attribute__((ext_vector_type(4)));

// ---- workspace layout (bytes). Zeroed region: [0, ZERO_BYTES) ----
#define OFS_HIST1   0u
#define OFS_HIST2   262144u
#define OFS_CNT1    524288u
#define OFS_SCAL    786432u     // u64[8]: 0=B 1=r 2=unused 3=candCount(u32)
#define ZERO_BYTES  786496u
#define OFS_BLKCNT  786496u     // FB_NB u32
#define OFS_BLKOFF  806032u     // FB_NB u32
#define OFS_OFFS1   825568u
#define OFS_BITS1   1087712u
#define OFS_BITS2   1887712u
#define OFS_SORT1   2687712u
#define OFS_CAND    4287712u    // 4096 u64
#define OFS_DROPB   4320480u    // 6250 u32 node drop bits
// total ~4.35 MB

struct U2pair { uint32_t a, b; };

// Threefry-2x32, 20 rounds — exact JAX/Random123 schedule.
__host__ __device__ constexpr U2pair tf2x32(uint32_t k0, uint32_t k1,
                                            uint32_t x0, uint32_t x1) {
  uint32_t ks[3] = { k0, k1, 0x1BD11BDAu ^ k0 ^ k1 };
  uint32_t v0 = x0 + ks[0];
  uint32_t v1 = x1 + ks[1];
  const int rotA[4] = {13, 15, 26, 6};
  const int rotB[4] = {17, 29, 16, 24};
  for (int i = 0; i < 5; ++i) {
    for (int j = 0; j < 4; ++j) {
      const int r = (i & 1) ? rotB[j] : rotA[j];
      v0 += v1;
      v1 = (v1 << r) | (v1 >> (32 - r));
      v1 ^= v0;
    }
    v0 += ks[(i + 1) % 3];
    v1 += ks[(i + 2) % 3] + (uint32_t)(i + 1);
  }
  return U2pair{v0, v1};
}

// Partitionable key chain from key(42) = (0,42):
//   split: keys[j] = tf(key, 0, j).  carried = keys[0], use1 = keys[1]
//   split #2 on carried: use2 = tf(carried, 0, 1)
constexpr U2pair CARRY1 = tf2x32(0u, 42u, 0u, 0u);
constexpr U2pair USE1   = tf2x32(0u, 42u, 0u, 1u);
constexpr uint32_t UK1A = USE1.a, UK1B = USE1.b;
constexpr U2pair USE2   = tf2x32(CARRY1.a, CARRY1.b, 0u, 1u);
constexpr uint32_t UK2A = USE2.a, UK2B = USE2.b;

// ---------------------------------------------------------------------------
// K1: bits1/bits2 (partitionable: bits[i] = out0^out1 of counter (0,i)) + hists.
__global__ void k_bits_hist(uint32_t* __restrict__ bits1,
                            uint32_t* __restrict__ bits2,
                            uint32_t* __restrict__ hist1,
                            uint32_t* __restrict__ hist2) {
  const int i = blockIdx.x * blockDim.x + threadIdx.x;
  if (i >= N_NODES) return;
  const U2pair r1 = tf2x32(UK1A, UK1B, 0u, (uint32_t)i);
  const U2pair r2 = tf2x32(UK2A, UK2B, 0u, (uint32_t)i);
  const uint32_t b1 = r1.a ^ r1.b;
  const uint32_t b2 = r2.a ^ r2.b;
  bits1[i] = b1;
  bits2[i] = b2;
  atomicAdd(&hist1[b1 >> 16], 1u);
  atomicAdd(&hist2[b2 >> 16], 1u);
}

// K2: dual histogram scan. Block 0: hist1 -> offs1. Block 1: hist2 + findSel.
__global__ __launch_bounds__(1024)
void k_scan_both(const uint32_t* __restrict__ hist1,
                 const uint32_t* __restrict__ hist2,
                 uint32_t* __restrict__ offs1,
                 uint64_t* __restrict__ scal) {
  const uint32_t* hist = (blockIdx.x == 0) ? hist1 : hist2;
  uint32_t* offs       = (blockIdx.x == 0) ? offs1 : nullptr;
  const int findSel    = (blockIdx.x == 0) ? 0 : 1;
  __shared__ uint32_t sums[1024];
  const int t = threadIdx.x;
  uint32_t s = 0;
  for (int j = 0; j < NBIN / 1024; ++j) s += hist[t * (NBIN / 1024) + j];
  sums[t] = s;
  __syncthreads();
  for (int d = 1; d < 1024; d <<= 1) {
    const uint32_t v = sums[t];
    const uint32_t add = (t >= d) ? sums[t - d] : 0u;
    __syncthreads();
    sums[t] = v + add;
    __syncthreads();
  }
  uint32_t run = (t == 0) ? 0u : sums[t - 1];
  for (int j = 0; j < NBIN / 1024; ++j) {
    const int b = t * (NBIN / 1024) + j;
    const uint32_t c = hist[b];
    if (offs) offs[b] = run;
    if (findSel && run <= (uint32_t)(N_DROP - 1) &&
        (uint32_t)(N_DROP - 1) < run + c) {
      scal[0] = (uint64_t)b;
      scal[1] = (uint64_t)((N_DROP - 1) - run);
    }
    run += c;
  }
}

// K3: scatter round-1 composite keys into buckets + gather round-2 candidates.
__global__ void k_scatter_cand(const uint32_t* __restrict__ bits1,
                               const uint32_t* __restrict__ bits2,
                               const uint32_t* __restrict__ offs1,
                               uint32_t* __restrict__ cnt1,
                               uint64_t* __restrict__ sort1,
                               const uint64_t* __restrict__ scal,
                               uint64_t* __restrict__ cand,
                               uint32_t* __restrict__ candCount) {
  const int i = blockIdx.x * blockDim.x + threadIdx.x;
  if (i >= N_NODES) return;
  const uint32_t k = bits1[i];
  const uint32_t b = k >> 16;
  const uint32_t slot = atomicAdd(&cnt1[b], 1u);
  sort1[offs1[b] + slot] = ((uint64_t)k << 32) | (uint32_t)i;

  const uint32_t B = (uint32_t)scal[0];
  const uint32_t k2 = bits2[i];
  if ((k2 >> 16) == B) {
    const uint32_t p = atomicAdd(candCount, 1u);
    if (p < 4096u) cand[p] = ((uint64_t)k2 << 32) | (uint32_t)i;
  }
}

// K4: fused rank1 + threshold + drop bits. Every block redundantly computes
// the 20000th-order-stat threshold T from the tiny candidate list (~3-6
// elems), then: j = rank1(i) (bucket-count), drop[i] = ((bits2[j],j) <= T),
// emitted via __ballot into the packed dropbits table. rank1 never hits HBM.
__global__ void k_rank1_drop(const uint32_t* __restrict__ bits1,
                             const uint32_t* __restrict__ offs1,
                             const uint32_t* __restrict__ hist1,
                             const uint64_t* __restrict__ sort1,
                             const uint32_t* __restrict__ bits2,
                             const uint64_t* __restrict__ cand,
                             const uint32_t* __restrict__ candCount,
                             const uint64_t* __restrict__ scal,
                             uint32_t* __restrict__ dropbits) {
  __shared__ uint64_t Tsh;
  if (threadIdx.x == 0) {
    const uint32_t n = *candCount;
    const uint32_t r = (uint32_t)scal[1];
    uint64_t T = 0;
    for (uint32_t a = 0; a < n; ++a) {
      const uint64_t v = cand[a];
      uint32_t c = 0;
      for (uint32_t b2_ = 0; b2_ < n; ++b2_) c += (cand[b2_] < v) ? 1u : 0u;
      if (c == r) { T = v; break; }
    }
    Tsh = T;
  }
  __syncthreads();
  const int i = blockIdx.x * blockDim.x + threadIdx.x;
  if (i >= N_NODES) return;   // OOB threads form whole waves (200192-200000=192)
  const uint32_t k = bits1[i];
  const uint32_t b = k >> 16;
  const uint64_t me = ((uint64_t)k << 32) | (uint32_t)i;
  const uint32_t start = offs1[b];
  const uint32_t cnt = hist1[b];
  uint32_t c = 0;
  for (uint32_t s = 0; s < cnt; ++s) c += (sort1[start + s] < me) ? 1u : 0u;
  const uint32_t j = start + c;                       // rank1(i)
  const uint64_t K2 = ((uint64_t)bits2[j] << 32) | j; // round-2 composite key
  const unsigned long long m = __ballot(K2 <= Tsh);
  const int lane = threadIdx.x & 63;
  if (lane == 0)       dropbits[i >> 5] = (uint32_t)m;
  else if (lane == 32) dropbits[i >> 5] = (uint32_t)(m >> 32);
}

// ---------------------------------------------------------------------------
// K5: per-block keep counts. 16 consecutive edges/thread, loads issued
// up-front (8 outstanding int4), barrier-free until the final 4-word reduce.
__global__ __launch_bounds__(FB_T)
void k_count(const int* __restrict__ ei,
             const uint32_t* __restrict__ dropbits,
             uint32_t* __restrict__ blkcnt) {
  const int b = blockIdx.x;
  const int t = threadIdx.x;
  const int64_t base = (int64_t)b * FB_EDGES + t * FB_PER;
  __shared__ uint32_t wsum[FB_T / 64];
  uint32_t myCount = 0;
  #pragma unroll
  for (int q = 0; q < 4; ++q) {
    const int64_t e = base + q * 4;
    if (e < NEDGE) {
      const int4 u4 = *(const int4*)(ei + e);
      const int4 i4 = *(const int4*)(ei + NEDGE + e);
      const int us[4] = {u4.x, u4.y, u4.z, u4.w};
      const int is_[4] = {i4.x, i4.y, i4.z, i4.w};
      #pragma unroll
      for (int j = 0; j < 4; ++j) {
        const uint32_t du = (dropbits[us[j] >> 5] >> (us[j] & 31)) & 1u;
        uint32_t keep = 1u;
        if (du) keep = 1u - ((dropbits[is_[j] >> 5] >> (is_[j] & 31)) & 1u);
        myCount += keep;
      }
    }
  }
  uint32_t v = myCount;
  #pragma unroll
  for (int d = 32; d >= 1; d >>= 1) v += __shfl_down(v, d);
  if ((t & 63) == 0) wsum[t >> 6] = v;
  __syncthreads();
  if (t == 0) blkcnt[b] = wsum[0] + wsum[1] + wsum[2] + wsum[3];
}

// K6: scan of block counts (FB_NB=4883 fits one 1024-thread block).
#define SB_PER ((FB_NB + 1023) / 1024)   // 5
__global__ __launch_bounds__(1024)
void k_scan_blocks(const uint32_t* __restrict__ blkcnt,
                   uint32_t* __restrict__ blkoff) {
  __shared__ uint32_t sums[1024];
  const int t = threadIdx.x;
  uint32_t loc[SB_PER];
  uint32_t s = 0;
  #pragma unroll
  for (int j = 0; j < SB_PER; ++j) {
    const int idx = t * SB_PER + j;
    const uint32_t c = (idx < FB_NB) ? blkcnt[idx] : 0u;
    loc[j] = c; s += c;
  }
  sums[t] = s;
  __syncthreads();
  for (int d = 1; d < 1024; d <<= 1) {
    const uint32_t v = sums[t];
    const uint32_t add = (t >= d) ? sums[t - d] : 0u;
    __syncthreads();
    sums[t] = v + add;
    __syncthreads();
  }
  uint32_t excl = (t == 0) ? 0u : sums[t - 1];
  #pragma unroll
  for (int j = 0; j < SB_PER; ++j) {
    const int idx = t * SB_PER + j;
    if (idx < FB_NB) blkoff[idx] = excl;
    excl += loc[j];
  }
}

// ---------------------------------------------------------------------------
// K7: stable scatter. 16 consecutive edges/thread -> one block-wide scan
// (2 barriers total), kept edges compacted in LDS, dumped as dense aligned
// nontemporal int4 stores at blkoff[b]. Dropped edges (-1) written at
// reverse-indexed tail slots NEDGE-1-(dropExcl+j), which tile [n_keep, NEDGE).
__global__ __launch_bounds__(FB_T)
void k_scatter(const int* __restrict__ ei,
               const uint32_t* __restrict__ dropbits,
               const uint32_t* __restrict__ blkoff,
               int* __restrict__ out) {
  __shared__ int ldsU[FB_EDGES];
  __shared__ int ldsI[FB_EDGES];
  __shared__ uint32_t wtot[FB_T / 64];
  const int b = blockIdx.x;
  const int t = threadIdx.x;
  const int lane = t & 63, wid = t >> 6;
  const int64_t blockStart = (int64_t)b * FB_EDGES;
  const int64_t tbase = blockStart + t * FB_PER;

  // phase 1: load 16 edges, build keep mask (all loads issued up-front)
  int us[FB_PER], is_[FB_PER];
  uint32_t flags = 0;
  #pragma unroll
  for (int q = 0; q < 4; ++q) {
    const int64_t e = tbase + q * 4;
    if (e < NEDGE) {
      const int4 u4 = *(const int4*)(ei + e);
      const int4 i4 = *(const int4*)(ei + NEDGE + e);
      us[q * 4 + 0] = u4.x; us[q * 4 + 1] = u4.y;
      us[q * 4 + 2] = u4.z; us[q * 4 + 3] = u4.w;
      is_[q * 4 + 0] = i4.x; is_[q * 4 + 1] = i4.y;
      is_[q * 4 + 2] = i4.z; is_[q * 4 + 3] = i4.w;
      #pragma unroll
      for (int j = 0; j < 4; ++j) {
        const int u = us[q * 4 + j], v = is_[q * 4 + j];
        const uint32_t du = (dropbits[u >> 5] >> (u & 31)) & 1u;
        uint32_t keep = 1u;
        if (du) keep = 1u - ((dropbits[v >> 5] >> (v & 31)) & 1u);
        flags |= keep << (q * 4 + j);
      }
    } else {
      #pragma unroll
      for (int j = 0; j < 4; ++j) { us[q * 4 + j] = 0; is_[q * 4 + j] = 0; }
    }
  }

  // single block-wide exclusive scan of per-thread keep counts
  const uint32_t c = __popc(flags);
  uint32_t incl = c;
  #pragma unroll
  for (int d = 1; d < 64; d <<= 1) {
    const uint32_t o = __shfl_up(incl, (unsigned)d);
    if (lane >= d) incl += o;
  }
  if (lane == 63) wtot[wid] = incl;
  __syncthreads();
  uint32_t wpref = 0, cnt = 0;
  #pragma unroll
  for (int w2 = 0; w2 < FB_T / 64; ++w2) {
    const uint32_t v = wtot[w2];
    if (w2 < wid) wpref += v;
    cnt += v;
  }
  uint32_t pos = wpref + incl - c;
  #pragma unroll
  for (int j = 0; j < FB_PER; ++j) {
    if ((flags >> j) & 1u) { ldsU[pos] = us[j]; ldsI[pos] = is_[j]; ++pos; }
  }
  __syncthreads();

  // phase 2a: dense nontemporal dump of kept edges [base, base+cnt)
  const uint32_t base = blkoff[b];
  const uint32_t end = base + cnt;
  const uint32_t aStart = (base + 3u) & ~3u;
  const uint32_t aEnd = end & ~3u;
  const uint32_t headEnd = (aStart < end) ? aStart : end;
  for (uint32_t g = base + t; g < headEnd; g += FB_T) {
    __builtin_nontemporal_store(ldsU[g - base], out + g);
    __builtin_nontemporal_store(ldsI[g - base], out + NEDGE + g);
  }
  if (end > aStart) {
    const uint32_t nVec = (aEnd - aStart) >> 2;
    for (uint32_t v = t; v < nVec; v += FB_T) {
      const uint32_t g = aStart + (v << 2);
      const uint32_t l = g - base;
      v4i vu, vi;
      vu.x = ldsU[l]; vu.y = ldsU[l + 1]; vu.z = ldsU[l + 2]; vu.w = ldsU[l + 3];
      vi.x = ldsI[l]; vi.y = ldsI[l + 1]; vi.z = ldsI[l + 2]; vi.w = ldsI[l + 3];
      __builtin_nontemporal_store(vu, (v4i*)(out + g));
      __builtin_nontemporal_store(vi, (v4i*)(out + NEDGE + g));
    }
    for (uint32_t g = aEnd + t; g < end; g += FB_T) {
      __builtin_nontemporal_store(ldsU[g - base], out + g);
      __builtin_nontemporal_store(ldsI[g - base], out + NEDGE + g);
    }
  }

  // phase 2b: -1 tail, reverse-indexed
  const uint32_t validEdges =
      (uint32_t)((NEDGE - blockStart) < (int64_t)FB_EDGES ? (NEDGE - blockStart)
                                                          : (int64_t)FB_EDGES);
  const uint32_t dropExcl = (uint32_t)blockStart - base;
  const uint32_t localDrops = validEdges - cnt;
  for (uint32_t j = t; j < localDrops; j += FB_T) {
    const uint32_t slot = (uint32_t)(NEDGE - 1) - (dropExcl + j);
    __builtin_nontemporal_store(-1, out + slot);
    __builtin_nontemporal_store(-1, out + NEDGE + slot);
  }
}

extern "C" void kernel_launch(void* const* d_in, const int* in_sizes, int n_in,
                              void* d_out, int out_size, void* d_ws,
                              size_t ws_size, hipStream_t stream) {
  (void)in_sizes; (void)n_in; (void)out_size; (void)ws_size;
  const int* ei = (const int*)d_in[0];
  int* out = (int*)d_out;
  char* ws = (char*)d_ws;

  uint32_t* hist1 = (uint32_t*)(ws + OFS_HIST1);
  uint32_t* hist2 = (uint32_t*)(ws + OFS_HIST2);
  uint32_t* cnt1  = (uint32_t*)(ws + OFS_CNT1);
  uint64_t* scal  = (uint64_t*)(ws + OFS_SCAL);
  uint32_t* candN  = (uint32_t*)(ws + OFS_SCAL + 24);  // scal[3] low
  uint32_t* blkcnt = (uint32_t*)(ws + OFS_BLKCNT);
  uint32_t* blkoff = (uint32_t*)(ws + OFS_BLKOFF);
  uint32_t* offs1 = (uint32_t*)(ws + OFS_OFFS1);
  uint32_t* bits1 = (uint32_t*)(ws + OFS_BITS1);
  uint32_t* bits2 = (uint32_t*)(ws + OFS_BITS2);
  uint64_t* sort1 = (uint64_t*)(ws + OFS_SORT1);
  uint64_t* cand  = (uint64_t*)(ws + OFS_CAND);
  uint32_t* dropb = (uint32_t*)(ws + OFS_DROPB);

  (void)hipMemsetAsync(d_ws, 0, ZERO_BYTES, stream);

  k_bits_hist<<<(N_NODES + 255) / 256, 256, 0, stream>>>(bits1, bits2, hist1, hist2);
  k_scan_both<<<2, 1024, 0, stream>>>(hist1, hist2, offs1, scal);
  k_scatter_cand<<<(N_NODES + 255) / 256, 256, 0, stream>>>(
      bits1, bits2, offs1, cnt1, sort1, scal, cand, candN);
  k_rank1_drop<<<(N_NODES + 255) / 256, 256, 0, stream>>>(
      bits1, offs1, hist1, sort1, bits2, cand, candN, scal, dropb);
  k_count<<<FB_NB, FB_T, 0, stream>>>(ei, dropb, blkcnt);
  k_scan_blocks<<<1, 1024, 0, stream>>>(blkcnt, blkoff);
  k_scatter<<<FB_NB, FB_T, 0, stream>>>(ei, dropb, blkoff, out);
}